// Round 14
// baseline (449.850 us; speedup 1.0000x reference)
//
#include <hip/hip_runtime.h>
#include <hip/hip_bf16.h>

using short8 = __attribute__((ext_vector_type(8))) short;
using f32x16 = __attribute__((ext_vector_type(16))) float;
using us4    = __attribute__((ext_vector_type(4))) unsigned short;

#define NHID 15872

__device__ __forceinline__ unsigned short f2bf(float f) {
  unsigned u = __builtin_bit_cast(unsigned, f);
  u += 0x7fff + ((u >> 16) & 1);          // RNE
  return (unsigned short)(u >> 16);
}
__device__ __forceinline__ short f2bf_hw(float f) {
  __hip_bfloat16 h = __float2bfloat16(f);
  return __builtin_bit_cast(short, h);
}
__device__ __forceinline__ float bf2f(unsigned short h) {
  return __builtin_bit_cast(float, ((unsigned)h) << 16);
}

// async global->LDS, 16B/lane. LDS dest = wave-uniform base + lane*16.
__device__ __forceinline__ void gload16(const void* g, void* l) {
  __builtin_amdgcn_global_load_lds(
      (const __attribute__((address_space(1))) unsigned int*)g,
      (__attribute__((address_space(3))) unsigned int*)l, 16, 0, 0);
}

// packed-A layout: (row,k) -> (k>>4)*4096 + (row + 256*((k>>3)&1))*8 + (k&7)
__device__ __forceinline__ size_t pk_idx(int row, int col) {
  return (size_t)(col >> 4) * 4096 +
         (size_t)(row + 256 * ((col >> 3) & 1)) * 8 + (col & 7);
}

// ---------------- kernel 0: x fp32 -> packed bf16 ----------------
__global__ void cvt_x_pack(const float* __restrict__ x, unsigned short* __restrict__ xpk) {
  int g = blockIdx.x * 256 + threadIdx.x;       // 16384 chunks of 8
  int row = g >> 6, k0 = (g & 63) * 8;
  const float* p = x + (size_t)row * 512 + k0;
  float4 a = *reinterpret_cast<const float4*>(p);
  float4 b = *reinterpret_cast<const float4*>(p + 4);
  us4 o0, o1;
  o0[0] = f2bf(a.x); o0[1] = f2bf(a.y); o0[2] = f2bf(a.z); o0[3] = f2bf(a.w);
  o1[0] = f2bf(b.x); o1[1] = f2bf(b.y); o1[2] = f2bf(b.z); o1[3] = f2bf(b.w);
  unsigned short* d = xpk + pk_idx(row, k0);
  *reinterpret_cast<us4*>(d)     = o0;
  *reinterpret_cast<us4*>(d + 4) = o1;
}

// ---------------- main GEMM v14: 256-thr WG, 3 WG/CU ----------------
// BM=256, BN=128, BK=32. 256 thr = 4 waves; wave w = rows w*64..+63 x all
// 128 cols; acc = 8 x f32x16 (128 AGPR), VGPR ~40 -> 3 waves/SIMD. Ring-3
// LDS (48 KB) -> 3 WG/CU = 3 DISJOINT B streams per CU. One barrier/tile;
// stage(t) drained by compute(t-1)'s implicit A-wait (1-phase slack, free
// in memory-bound regime). OUTMODE: 0 packed-bf16 final, 1 bf16 partials,
// 2 rowmajor final.

#define WAITV(N) asm volatile("s_waitcnt vmcnt(" #N ")" ::: "memory")

// B tile 32k x 128col fp32: wave w stages rows w*8..w*8+7 (4 x 1KB instrs)
#define STAGEB(BUF, T) do { _Pragma("unroll") \
  for (int j_ = 0; j_ < 4; ++j_) \
    gload16(bsrc + ((size_t)(T) * 32 + 2 * j_) * NHID, \
            &Blds[BUF][(w * 8 + 2 * j_) * 128]); \
} while (0)

#define LOADA(T) do { \
    const unsigned short* ap_ = asrc + (size_t)(T) * 8192; \
    rA[0] = *reinterpret_cast<const short8*>(ap_); \
    rA[1] = *reinterpret_cast<const short8*>(ap_ + 4096); \
    rA[2] = *reinterpret_cast<const short8*>(ap_ + 256); \
    rA[3] = *reinterpret_cast<const short8*>(ap_ + 4096 + 256); \
  } while (0)

#define COMPUTE(BC) do { \
    const float* bb_ = &Blds[BC][0]; \
    _Pragma("unroll") \
    for (int ks_ = 0; ks_ < 2; ++ks_) { \
      _Pragma("unroll") \
      for (int nb_ = 0; nb_ < 4; ++nb_) { \
        float tf_[8]; \
        _Pragma("unroll") \
        for (int jj_ = 0; jj_ < 8; ++jj_) \
          tf_[jj_] = bb_[(ks_ * 16 + hi * 8 + jj_) * 128 + nb_ * 32 + l31]; \
        short8 bfr_; \
        _Pragma("unroll") \
        for (int jj_ = 0; jj_ < 8; ++jj_) bfr_[jj_] = f2bf_hw(tf_[jj_]); \
        acc[nb_]     = __builtin_amdgcn_mfma_f32_32x32x16_bf16(rA[ks_],     bfr_, acc[nb_],     0, 0, 0); \
        acc[4 + nb_] = __builtin_amdgcn_mfma_f32_32x32x16_bf16(rA[2 + ks_], bfr_, acc[4 + nb_], 0, 0, 0); \
      } \
    } \
  } while (0)

template<int OUTMODE, bool SWZ>
__global__ __launch_bounds__(256, 3)
void gemm_v14(const unsigned short* __restrict__ Apk, int KC,
              const float* __restrict__ B, const float* __restrict__ bias,
              unsigned short* __restrict__ Cf, unsigned short* __restrict__ Cpb)
{
  __shared__ float Blds[3][32 * 128];   // 48 KB ring-3

  int nidx, ks0;
  if (SWZ) {
    int b = blockIdx.x;        // 1984 = 124 n x 16 k; xcd b%8 -> 2 A-slices/XCD-L2
    ks0  = b & 15;
    nidx = b >> 4;
  } else {
    nidx = blockIdx.x; ks0 = blockIdx.y;
  }
  const int n0   = nidx * 128;
  const int k0   = ks0 * KC;
  const int tid  = threadIdx.x;
  const int w    = tid >> 6;
  const int lane = tid & 63;
  const int l31  = lane & 31;
  const int hi   = lane >> 5;

  f32x16 acc[8] = {};   // [rb*4 + nb]
  short8 rA[4];         // [rb*2 + ks] layout: [0]=rb0ks0 [1]=rb0ks1 [2]=rb1ks0 [3]=rb1ks1

  // B stage src: rows k0 + t*32 + w*8 + 2j + hi, cols n0 + l31*4 (1 KB/instr)
  const float* bsrc = B + (size_t)(k0 + w * 8 + hi) * NHID + n0 + l31 * 4;
  // A frag src (packed): rows w*64 + rb*32 + l31, k = t*32 + ks*16 + hi*8 + e
  const unsigned short* asrc = Apk + (size_t)(k0 >> 4) * 4096 +
                               (size_t)(w * 64 + l31 + 256 * hi) * 8;

  const int NT = KC >> 5;   // GEMM1: 8; GEMM2: 31; fallback: 16/496

  STAGEB(0, 0);
  STAGEB(1, 1);

  int bc = 0;
  for (int t = 0; t < NT; ++t) {
    WAITV(4);                                // t=0: drain stage(0); else no-op
    __builtin_amdgcn_sched_barrier(0);
    __builtin_amdgcn_s_barrier();            // all waves' stage(t) landed
    LOADA(t);
    if (t + 2 < NT) { int sb_ = bc >= 1 ? bc - 1 : 2; STAGEB(sb_, t + 2); }
    COMPUTE(bc);
    bc = bc == 2 ? 0 : bc + 1;
  }

  // epilogue: verified mapping col=n0+nb*32+l31, row=w*64+rb*32+(reg&3)+8*(reg>>2)+4*hi
#pragma unroll
  for (int rb = 0; rb < 2; ++rb) {
#pragma unroll
    for (int nb = 0; nb < 4; ++nb) {
      int col = n0 + nb * 32 + l31;
      float bv = (OUTMODE != 1) ? bias[col] : 0.f;
#pragma unroll
      for (int reg = 0; reg < 16; ++reg) {
        int row = w * 64 + rb * 32 + (reg & 3) + 8 * (reg >> 2) + 4 * hi;
        float v = acc[rb * 4 + nb][reg];
        if (OUTMODE == 0) {
          v += bv; v = v > 0.f ? v : 0.f;
          Cf[pk_idx(row, col)] = f2bf(v);
        } else if (OUTMODE == 1) {
          Cpb[(size_t)ks0 * 256 * NHID + (size_t)row * NHID + col] = f2bf(v);
        } else {
          v += bv; v = v > 0.f ? v : 0.f;
          Cf[(size_t)row * NHID + col] = f2bf(v);
        }
      }
    }
  }
}

// ---------------- reduce bf16 partials: out = relu(sum + bias) -> bf16 ----------------
template<bool PACK>
__global__ void reduce_hb(const unsigned short* __restrict__ part,
                          const float* __restrict__ bias,
                          unsigned short* __restrict__ out, int S) {
  int g8 = blockIdx.x * 256 + threadIdx.x;     // < 256*1984 (chunks of 8)
  int row = g8 / 1984;
  int c   = (g8 - row * 1984) * 8;
  size_t off = (size_t)row * NHID + c;
  float s[8] = {0.f, 0.f, 0.f, 0.f, 0.f, 0.f, 0.f, 0.f};
  for (int k = 0; k < S; ++k) {
    short8 p = *reinterpret_cast<const short8*>(part + (size_t)k * 256 * NHID + off);
#pragma unroll
    for (int j = 0; j < 8; ++j) s[j] += bf2f((unsigned short)p[j]);
  }
  short8 o;
#pragma unroll
  for (int j = 0; j < 8; ++j) {
    float v = s[j] + bias[c + j];
    v = v > 0.f ? v : 0.f;
    o[j] = (short)f2bf(v);
  }
  if (PACK) *reinterpret_cast<short8*>(out + pk_idx(row, c)) = o;   // c%8==0 -> contiguous
  else      *reinterpret_cast<short8*>(out + off) = o;
}

// ---------------- fold Wout [15872][992] -> Wv [15872][32] ----------------
__global__ void wv_fold(const float* __restrict__ Wout, float* __restrict__ Wv) {
  int g = blockIdx.x * 256 + threadIdx.x;
  int k = g >> 5, c = g & 31;
  const float* row = Wout + (size_t)k * 992;
  float s = 0.f;
#pragma unroll
  for (int o = 0; o < 32; ++o) {
    if (o == c) continue;
    int i = c < o ? c : o;
    int j = c < o ? o : c;
    int p = 31 * i - (i * (i - 1)) / 2 + (j - i - 1);
    s += row[2 * p + (c > o ? 1 : 0)];
  }
  Wv[g] = s;
}

// ---------------- votes partial = h2 @ Wv, K-split 32 ----------------
__global__ void votes_partial(const unsigned short* __restrict__ h2,
                              const float* __restrict__ Wv,
                              float* __restrict__ part) {
  int bm = blockIdx.x >> 5;
  int ks = blockIdx.x & 31;
  int r  = bm * 8 + (threadIdx.x >> 5);
  int c  = threadIdx.x & 31;
  const unsigned short* hrow = h2 + (size_t)r * NHID + ks * 496;
  const float* wp = Wv + (size_t)(ks * 496) * 32 + c;
  float s = 0.f;
  for (int k0 = 0; k0 < 496; k0 += 8) {
    short8 hv = *reinterpret_cast<const short8*>(hrow + k0);
#pragma unroll
    for (int j = 0; j < 8; ++j)
      s += bf2f((unsigned short)hv[j]) * wp[(size_t)(k0 + j) * 32];
  }
  part[(size_t)(ks * 256 + r) * 32 + c] = s;
}

// ---------------- reduce votes + bias-fold ----------------
__global__ void votes_reduce(const float* __restrict__ part,
                             const float* __restrict__ bout,
                             float* __restrict__ out) {
  int g = blockIdx.x * 256 + threadIdx.x;
  int c = g & 31;
  float s = 0.f;
#pragma unroll
  for (int ks = 0; ks < 32; ++ks) s += part[(size_t)ks * 8192 + g];
  float bv = 0.f;
#pragma unroll
  for (int o = 0; o < 32; ++o) {
    if (o == c) continue;
    int i = c < o ? c : o;
    int j = c < o ? o : c;
    int p = 31 * i - (i * (i - 1)) / 2 + (j - i - 1);
    bv += bout[2 * p + (c > o ? 1 : 0)];
  }
  out[g] = s + bv;
}

extern "C" void kernel_launch(void* const* d_in, const int* in_sizes, int n_in,
                              void* d_out, int out_size, void* d_ws, size_t ws_size,
                              hipStream_t stream) {
  const float* x    = (const float*)d_in[0];
  const float* W1   = (const float*)d_in[1];
  const float* b1   = (const float*)d_in[2];
  const float* W2   = (const float*)d_in[3];
  const float* b2   = (const float*)d_in[4];
  const float* Wout = (const float*)d_in[5];
  const float* bout = (const float*)d_in[6];
  float* out = (float*)d_out;

  char* ws = (char*)d_ws;
  unsigned short* xpk  = (unsigned short*)(ws);                     // 262144
  unsigned short* h1pk = (unsigned short*)(ws + 262144);            // 8126464
  unsigned short* h2   = (unsigned short*)(ws + 8388608);           // 8126464
  float*          Wv   = (float*)(ws + 16515072);                   // 2031616
  float*          part = (float*)(ws + 18546688);                   // 1048576
  unsigned short* pb   = (unsigned short*)(ws + 19595264);          // 16*256*NHID*2 = 130 MB

  const size_t PARTB = (size_t)256 * NHID * 2;   // 8,126,464 per bf16 partial
  const bool split = ws_size >= 19595264ull + 16 * PARTB;

  hipLaunchKernelGGL(cvt_x_pack, dim3(64), dim3(256), 0, stream, x, xpk);
  if (split) {
    // GEMM1: K=512 split 2 ways -> bf16 partials -> packed h1
    hipLaunchKernelGGL((gemm_v14<1, false>), dim3(124, 2), dim3(256), 0, stream,
                       xpk, 256, W1, (const float*)nullptr,
                       (unsigned short*)nullptr, pb);
    hipLaunchKernelGGL((reduce_hb<true>), dim3(1984), dim3(256), 0, stream,
                       pb, b1, h1pk, 2);
    // GEMM2: K=15872 split 16 ways, 1984 WGs at 3/CU (smeared rounds)
    hipLaunchKernelGGL((gemm_v14<1, true>), dim3(1984), dim3(256), 0, stream,
                       h1pk, 992, W2, (const float*)nullptr,
                       (unsigned short*)nullptr, pb);
    hipLaunchKernelGGL((reduce_hb<false>), dim3(1984), dim3(256), 0, stream,
                       pb, b2, h2, 16);
  } else {
    hipLaunchKernelGGL((gemm_v14<0, false>), dim3(124, 1), dim3(256), 0, stream,
                       xpk, 512, W1, b1, h1pk, (unsigned short*)nullptr);
    hipLaunchKernelGGL((gemm_v14<2, false>), dim3(124, 1), dim3(256), 0, stream,
                       h1pk, NHID, W2, b2, h2, (unsigned short*)nullptr);
  }
  hipLaunchKernelGGL(wv_fold,       dim3(1984), dim3(256), 0, stream, Wout, Wv);
  hipLaunchKernelGGL(votes_partial, dim3(1024), dim3(256), 0, stream, h2, Wv, part);
  hipLaunchKernelGGL(votes_reduce,  dim3(32),   dim3(256), 0, stream, part, bout, out);
}

// Round 15
// 392.992 us; speedup vs baseline: 1.1447x; 1.1447x over previous
//
#include <hip/hip_runtime.h>
#include <hip/hip_bf16.h>

using short8 = __attribute__((ext_vector_type(8))) short;
using f32x16 = __attribute__((ext_vector_type(16))) float;
using us4    = __attribute__((ext_vector_type(4))) unsigned short;

#define NHID 15872

__device__ __forceinline__ unsigned short f2bf(float f) {
  unsigned u = __builtin_bit_cast(unsigned, f);
  u += 0x7fff + ((u >> 16) & 1);          // RNE
  return (unsigned short)(u >> 16);
}
__device__ __forceinline__ short f2bf_hw(float f) {
  __hip_bfloat16 h = __float2bfloat16(f);
  return __builtin_bit_cast(short, h);
}
__device__ __forceinline__ float bf2f(unsigned short h) {
  return __builtin_bit_cast(float, ((unsigned)h) << 16);
}

// async global->LDS, 16B/lane. LDS dest = wave-uniform base + lane*16.
__device__ __forceinline__ void gload16(const void* g, void* l) {
  __builtin_amdgcn_global_load_lds(
      (const __attribute__((address_space(1))) unsigned int*)g,
      (__attribute__((address_space(3))) unsigned int*)l, 16, 0, 0);
}
// non-temporal variant (aux bit1 = NT): zero-reuse B stream, don't thrash L2
__device__ __forceinline__ void gload16nt(const void* g, void* l) {
  __builtin_amdgcn_global_load_lds(
      (const __attribute__((address_space(1))) unsigned int*)g,
      (__attribute__((address_space(3))) unsigned int*)l, 16, 0, 2);
}

// packed-A layout: (row,k) -> (k>>4)*4096 + (row + 256*((k>>3)&1))*8 + (k&7)
__device__ __forceinline__ size_t pk_idx(int row, int col) {
  return (size_t)(col >> 4) * 4096 +
         (size_t)(row + 256 * ((col >> 3) & 1)) * 8 + (col & 7);
}

// ---------------- kernel 0: x fp32 -> packed bf16 ----------------
__global__ void cvt_x_pack(const float* __restrict__ x, unsigned short* __restrict__ xpk) {
  int g = blockIdx.x * 256 + threadIdx.x;       // 16384 chunks of 8
  int row = g >> 6, k0 = (g & 63) * 8;
  const float* p = x + (size_t)row * 512 + k0;
  float4 a = *reinterpret_cast<const float4*>(p);
  float4 b = *reinterpret_cast<const float4*>(p + 4);
  us4 o0, o1;
  o0[0] = f2bf(a.x); o0[1] = f2bf(a.y); o0[2] = f2bf(a.z); o0[3] = f2bf(a.w);
  o1[0] = f2bf(b.x); o1[1] = f2bf(b.y); o1[2] = f2bf(b.z); o1[3] = f2bf(b.w);
  unsigned short* d = xpk + pk_idx(row, k0);
  *reinterpret_cast<us4*>(d)     = o0;
  *reinterpret_cast<us4*>(d + 4) = o1;
}

// ---------------- main GEMM v15 (= v12 + NT-B + XCD-pinned A slices) ----------------
// BM=256, BN=128, BK=32. 512 thr = 8 waves (4m x 2n): wave = 64 rows x 64 cols,
// acc = 4 x f32x16 (64 AGPR). B-only LDS ring-3 (48 KB) -> 2 WG/CU, DISJOINT B.
// B staged with NT policy (no L2 pollution); A per-tile global->reg from the
// packed image, L2-resident (1 MB slice per XCD under ks0 = xcd decode).
// OUTMODE: 0 = bias+relu -> packed bf16, 1 = bf16 partials, 2 = rowmajor bf16.

#define WAITV(N) asm volatile("s_waitcnt vmcnt(" #N ")" ::: "memory")

// B tile 32k x 128col fp32: wave w stages rows w*4..w*4+3 (2 instrs x 2 rows)
#define STAGEB(BUF, T) do { \
    gload16nt(bsrc + (size_t)(T) * 32 * NHID,       &Blds[BUF][(w * 4 + 0) * 128]); \
    gload16nt(bsrc + ((size_t)(T) * 32 + 2) * NHID, &Blds[BUF][(w * 4 + 2) * 128]); \
  } while (0)

#define LOADA(T) do { \
    const unsigned short* ap_ = asrc + (size_t)(T) * 8192; \
    rA[0] = *reinterpret_cast<const short8*>(ap_); \
    rA[1] = *reinterpret_cast<const short8*>(ap_ + 4096); \
    rA[2] = *reinterpret_cast<const short8*>(ap_ + 256); \
    rA[3] = *reinterpret_cast<const short8*>(ap_ + 4096 + 256); \
  } while (0)

#define COMPUTE(BC) do { \
    const float* bb_ = &Blds[BC][0]; \
    _Pragma("unroll") \
    for (int ks_ = 0; ks_ < 2; ++ks_) { \
      short8 bfr_[2]; \
      _Pragma("unroll") \
      for (int nb_ = 0; nb_ < 2; ++nb_) { \
        float tf_[8]; \
        _Pragma("unroll") \
        for (int jj_ = 0; jj_ < 8; ++jj_) \
          tf_[jj_] = bb_[(ks_ * 16 + hi * 8 + jj_) * 128 + wn * 64 + nb_ * 32 + l31]; \
        _Pragma("unroll") \
        for (int jj_ = 0; jj_ < 8; ++jj_) bfr_[nb_][jj_] = f2bf_hw(tf_[jj_]); \
      } \
      acc[0] = __builtin_amdgcn_mfma_f32_32x32x16_bf16(rA[ks_],     bfr_[0], acc[0], 0, 0, 0); \
      acc[1] = __builtin_amdgcn_mfma_f32_32x32x16_bf16(rA[ks_],     bfr_[1], acc[1], 0, 0, 0); \
      acc[2] = __builtin_amdgcn_mfma_f32_32x32x16_bf16(rA[2 + ks_], bfr_[0], acc[2], 0, 0, 0); \
      acc[3] = __builtin_amdgcn_mfma_f32_32x32x16_bf16(rA[2 + ks_], bfr_[1], acc[3], 0, 0, 0); \
    } \
  } while (0)

template<int OUTMODE, bool SWZ>
__global__ __launch_bounds__(512, 4)
void gemm_v15(const unsigned short* __restrict__ Apk, int KC,
              const float* __restrict__ B, const float* __restrict__ bias,
              unsigned short* __restrict__ Cf, unsigned short* __restrict__ Cpb)
{
  __shared__ float Blds[3][32 * 128];   // 48 KB ring-3

  int nidx, ks0;
  if (SWZ) {
    int b = blockIdx.x;                  // 992 = 124 n x 8 k
    ks0  = b & 7;                        // ks0 == XCD id: one 1MB A-slice per XCD-L2
    nidx = b >> 3;                       // 0..123; same-CU pair differs in n only
  } else {
    nidx = blockIdx.x; ks0 = blockIdx.y;
  }
  const int n0   = nidx * 128;
  const int k0   = ks0 * KC;
  const int tid  = threadIdx.x;
  const int w    = tid >> 6;
  const int lane = tid & 63;
  const int l31  = lane & 31;
  const int hi   = lane >> 5;
  const int wm   = w >> 1;     // rows wm*64..+63
  const int wn   = w & 1;      // cols wn*64..+63

  f32x16 acc[4] = {};   // [rb*2+nb], lives in AGPR
  short8 rA[4];

  // B stage src: row = k0 + t*32 + w*4 + {0,2} + hi, col = n0 + l31*4
  const float* bsrc = B + (size_t)(k0 + w * 4 + hi) * NHID + n0 + l31 * 4;
  // A frag src (packed): + (t*2+ks)*4096 + rb*256 shorts
  const unsigned short* asrc = Apk + (size_t)(k0 >> 4) * 4096 +
                               (size_t)(wm * 64 + l31 + 256 * hi) * 8;

  const int NT = KC >> 5;   // GEMM1: 8; GEMM2: 62; fallback: 16/496

  STAGEB(0, 0);
  STAGEB(1, 1);

  int bc = 0;
  for (int t = 0; t < NT; ++t) {
    if (t + 1 < NT) { WAITV(2); } else { WAITV(0); }
    __builtin_amdgcn_sched_barrier(0);
    __builtin_amdgcn_s_barrier();            // all waves' stage(t) landed
    LOADA(t);                                 // issued BEFORE next stage
    if (t + 2 < NT) { int sb_ = bc >= 1 ? bc - 1 : 2; STAGEB(sb_, t + 2); }
    COMPUTE(bc);
    bc = bc == 2 ? 0 : bc + 1;
  }

  // epilogue: verified mapping col=base+l31, row=(reg&3)+8*(reg>>2)+4*hi
#pragma unroll
  for (int rb = 0; rb < 2; ++rb) {
#pragma unroll
    for (int nb = 0; nb < 2; ++nb) {
      int col = n0 + wn * 64 + nb * 32 + l31;
      float bv = (OUTMODE != 1) ? bias[col] : 0.f;
#pragma unroll
      for (int reg = 0; reg < 16; ++reg) {
        int row = wm * 64 + rb * 32 + (reg & 3) + 8 * (reg >> 2) + 4 * hi;
        float v = acc[rb * 2 + nb][reg];
        if (OUTMODE == 0) {
          v += bv; v = v > 0.f ? v : 0.f;
          Cf[pk_idx(row, col)] = f2bf(v);
        } else if (OUTMODE == 1) {
          Cpb[(size_t)ks0 * 256 * NHID + (size_t)row * NHID + col] = f2bf(v);
        } else {
          v += bv; v = v > 0.f ? v : 0.f;
          Cf[(size_t)row * NHID + col] = f2bf(v);
        }
      }
    }
  }
}

// ---------------- reduce bf16 partials: out = relu(sum + bias) -> bf16 ----------------
template<bool PACK>
__global__ void reduce_hb(const unsigned short* __restrict__ part,
                          const float* __restrict__ bias,
                          unsigned short* __restrict__ out, int S) {
  int g8 = blockIdx.x * 256 + threadIdx.x;     // < 256*1984 (chunks of 8)
  int row = g8 / 1984;
  int c   = (g8 - row * 1984) * 8;
  size_t off = (size_t)row * NHID + c;
  float s[8] = {0.f, 0.f, 0.f, 0.f, 0.f, 0.f, 0.f, 0.f};
  for (int k = 0; k < S; ++k) {
    short8 p = *reinterpret_cast<const short8*>(part + (size_t)k * 256 * NHID + off);
#pragma unroll
    for (int j = 0; j < 8; ++j) s[j] += bf2f((unsigned short)p[j]);
  }
  short8 o;
#pragma unroll
  for (int j = 0; j < 8; ++j) {
    float v = s[j] + bias[c + j];
    v = v > 0.f ? v : 0.f;
    o[j] = (short)f2bf(v);
  }
  if (PACK) *reinterpret_cast<short8*>(out + pk_idx(row, c)) = o;   // c%8==0 -> contiguous
  else      *reinterpret_cast<short8*>(out + off) = o;
}

// ---------------- fold Wout [15872][992] -> Wv [15872][32] ----------------
__global__ void wv_fold(const float* __restrict__ Wout, float* __restrict__ Wv) {
  int g = blockIdx.x * 256 + threadIdx.x;
  int k = g >> 5, c = g & 31;
  const float* row = Wout + (size_t)k * 992;
  float s = 0.f;
#pragma unroll
  for (int o = 0; o < 32; ++o) {
    if (o == c) continue;
    int i = c < o ? c : o;
    int j = c < o ? o : c;
    int p = 31 * i - (i * (i - 1)) / 2 + (j - i - 1);
    s += row[2 * p + (c > o ? 1 : 0)];
  }
  Wv[g] = s;
}

// ---------------- votes partial = h2 @ Wv, K-split 32 ----------------
__global__ void votes_partial(const unsigned short* __restrict__ h2,
                              const float* __restrict__ Wv,
                              float* __restrict__ part) {
  int bm = blockIdx.x >> 5;
  int ks = blockIdx.x & 31;
  int r  = bm * 8 + (threadIdx.x >> 5);
  int c  = threadIdx.x & 31;
  const unsigned short* hrow = h2 + (size_t)r * NHID + ks * 496;
  const float* wp = Wv + (size_t)(ks * 496) * 32 + c;
  float s = 0.f;
  for (int k0 = 0; k0 < 496; k0 += 8) {
    short8 hv = *reinterpret_cast<const short8*>(hrow + k0);
#pragma unroll
    for (int j = 0; j < 8; ++j)
      s += bf2f((unsigned short)hv[j]) * wp[(size_t)(k0 + j) * 32];
  }
  part[(size_t)(ks * 256 + r) * 32 + c] = s;
}

// ---------------- reduce votes + bias-fold ----------------
__global__ void votes_reduce(const float* __restrict__ part,
                             const float* __restrict__ bout,
                             float* __restrict__ out) {
  int g = blockIdx.x * 256 + threadIdx.x;
  int c = g & 31;
  float s = 0.f;
#pragma unroll
  for (int ks = 0; ks < 32; ++ks) s += part[(size_t)ks * 8192 + g];
  float bv = 0.f;
#pragma unroll
  for (int o = 0; o < 32; ++o) {
    if (o == c) continue;
    int i = c < o ? c : o;
    int j = c < o ? o : c;
    int p = 31 * i - (i * (i - 1)) / 2 + (j - i - 1);
    bv += bout[2 * p + (c > o ? 1 : 0)];
  }
  out[g] = s + bv;
}

extern "C" void kernel_launch(void* const* d_in, const int* in_sizes, int n_in,
                              void* d_out, int out_size, void* d_ws, size_t ws_size,
                              hipStream_t stream) {
  const float* x    = (const float*)d_in[0];
  const float* W1   = (const float*)d_in[1];
  const float* b1   = (const float*)d_in[2];
  const float* W2   = (const float*)d_in[3];
  const float* b2   = (const float*)d_in[4];
  const float* Wout = (const float*)d_in[5];
  const float* bout = (const float*)d_in[6];
  float* out = (float*)d_out;

  char* ws = (char*)d_ws;
  unsigned short* xpk  = (unsigned short*)(ws);                     // 262144
  unsigned short* h1pk = (unsigned short*)(ws + 262144);            // 8126464
  unsigned short* h2   = (unsigned short*)(ws + 8388608);           // 8126464
  float*          Wv   = (float*)(ws + 16515072);                   // 2031616
  float*          part = (float*)(ws + 18546688);                   // 1048576
  unsigned short* pb   = (unsigned short*)(ws + 19595264);          // 8*256*NHID*2 = 65 MB

  const size_t PARTB = (size_t)256 * NHID * 2;   // 8,126,464 per bf16 partial
  const bool split = ws_size >= 19595264ull + 8 * PARTB;

  hipLaunchKernelGGL(cvt_x_pack, dim3(64), dim3(256), 0, stream, x, xpk);
  if (split) {
    // GEMM1: K=512 split 2 ways -> bf16 partials -> packed h1
    hipLaunchKernelGGL((gemm_v15<1, false>), dim3(124, 2), dim3(512), 0, stream,
                       xpk, 256, W1, (const float*)nullptr,
                       (unsigned short*)nullptr, pb);
    hipLaunchKernelGGL((reduce_hb<true>), dim3(1984), dim3(256), 0, stream,
                       pb, b1, h1pk, 2);
    // GEMM2: K=15872 split 8 ways; ks0 = XCD id (A-slice pinned per XCD-L2),
    // same-CU pair = disjoint n panels; B staged non-temporal.
    hipLaunchKernelGGL((gemm_v15<1, true>), dim3(992), dim3(512), 0, stream,
                       h1pk, 1984, W2, (const float*)nullptr,
                       (unsigned short*)nullptr, pb);
    hipLaunchKernelGGL((reduce_hb<false>), dim3(1984), dim3(256), 0, stream,
                       pb, b2, h2, 8);
  } else {
    hipLaunchKernelGGL((gemm_v15<0, false>), dim3(124, 1), dim3(512), 0, stream,
                       xpk, 512, W1, b1, h1pk, (unsigned short*)nullptr);
    hipLaunchKernelGGL((gemm_v15<2, false>), dim3(124, 1), dim3(512), 0, stream,
                       h1pk, NHID, W2, b2, h2, (unsigned short*)nullptr);
  }
  hipLaunchKernelGGL(wv_fold,       dim3(1984), dim3(256), 0, stream, Wout, Wv);
  hipLaunchKernelGGL(votes_partial, dim3(1024), dim3(256), 0, stream, h2, Wv, part);
  hipLaunchKernelGGL(votes_reduce,  dim3(32),   dim3(256), 0, stream, part, bout, out);
}